// Round 3
// baseline (698.046 us; speedup 1.0000x reference)
//
#include <hip/hip_runtime.h>

namespace {

constexpr int LMAX  = 10;
constexpr int NPART = 4;
// Greedy-balanced partition of l into 4 parts by inner-term count:
// P0{10,3}, P1{9,4}, P2{8,5,1}, P3{7,6,2,0}
constexpr int PART_OF_L[LMAX + 1] = {3, 2, 3, 0, 1, 2, 3, 3, 2, 1, 0};
constexpr double PI_D = 3.14159265358979323846;

constexpr double FACT[LMAX + 1] = {1., 1., 2., 6., 24., 120., 720., 5040., 40320., 362880., 3628800.};

constexpr double dfact(int n) {
    double r = 1.0;
    for (int i = 2; i <= n; ++i) r *= (double)i;
    return r;
}
constexpr double csqrt(double x) {
    if (x <= 0.0) return 0.0;
    double g = x > 1.0 ? x : 1.0;
    for (int i = 0; i < 100; ++i) g = 0.5 * (g + x / g);
    return g;
}

// ---- term coefficients ----------------------------------------------------
constexpr float coef_r(int l, int m, int p) {
    const int q = p - m, s = l - p - q;
    return (float)(1.0 / (FACT[p] * FACT[q] * FACT[s]));
}
constexpr float coef_i(int l, int m, int p) {
    const int q = p - m;
    const float c = coef_r(l, m, p);
    return (q & 1) ? -c : c;
}

// Dedup all signed coefficient values into a pack passed as a KERNEL ARG.
// Kernarg values are runtime-opaque -> they live in SGPRs (separate budget),
// and v_fma_f32 can read one SGPR source: no per-term literal v_mov remat.
constexpr int MAXC = 320;
struct CoefsN {
    float v[MAXC];
    int   n;
};
constexpr CoefsN build_coefs() {
    CoefsN b{};
    b.n = 0;
    for (int l = 0; l <= LMAX; ++l)
        for (int m = 0; m <= l; ++m)
            for (int p = m; 2 * p <= l + m; ++p) {
                const float cr = coef_r(l, m, p);
                bool found = false;
                for (int i = 0; i < b.n; ++i)
                    if (b.v[i] == cr) { found = true; break; }
                if (!found) b.v[b.n++] = cr;
                if (m > 0) {
                    const float ci = coef_i(l, m, p);
                    found = false;
                    for (int i = 0; i < b.n; ++i)
                        if (b.v[i] == ci) { found = true; break; }
                    if (!found) b.v[b.n++] = ci;
                }
            }
    return b;
}
constexpr CoefsN CB = build_coefs();
constexpr int    NC = CB.n;

struct Coefs {
    float v[NC];
};
constexpr Coefs make_coef_arg() {
    Coefs c{};
    for (int i = 0; i < NC; ++i) c.v[i] = CB.v[i];
    return c;
}
constexpr Coefs COEF_ARG = make_coef_arg();

constexpr int cfind(float x) {
    for (int i = 0; i < CB.n; ++i)
        if (CB.v[i] == x) return i;
    return -1;
}
constexpr int cidx_r(int l, int m, int p) { return cfind(coef_r(l, m, p)); }
constexpr int cidx_i(int l, int m, int p) { return cfind(coef_i(l, m, p)); }

// ---- pair enumerations (u: p>=q, v: p>q; p+q<=LMAX) -----------------------
constexpr int pu_idx(int p, int q) {
    int idx = 0;
    for (int pp = 0; pp <= LMAX; ++pp)
        for (int qq = 0; qq <= pp; ++qq) {
            if (pp + qq > LMAX) continue;
            if (pp == p && qq == q) return idx;
            ++idx;
        }
    return -1;
}
constexpr int pu_count() {
    int idx = 0;
    for (int pp = 0; pp <= LMAX; ++pp)
        for (int qq = 0; qq <= pp; ++qq)
            if (pp + qq <= LMAX) ++idx;
    return idx;
}
constexpr int pv_idx(int p, int q) {
    int idx = 0;
    for (int pp = 0; pp <= LMAX; ++pp)
        for (int qq = 0; qq < pp; ++qq) {
            if (pp + qq > LMAX) continue;
            if (pp == p && qq == q) return idx;
            ++idx;
        }
    return -1;
}
constexpr int pv_count() {
    int idx = 0;
    for (int pp = 0; pp <= LMAX; ++pp)
        for (int qq = 0; qq < pp; ++qq)
            if (pp + qq <= LMAX) ++idx;
    return idx;
}

// ---- per-part accumulator slot layout ------------------------------------
constexpr int slot_base(int part, int l) {
    int c = 0;
    for (int ll = 0; ll < l; ++ll)
        if (PART_OF_L[ll] == part) c += 2 * ll + 1;
    return c;
}
constexpr int nacc_part(int part) {
    int c = 0;
    for (int l = 0; l <= LMAX; ++l)
        if (PART_OF_L[l] == part) c += 2 * l + 1;
    return c;
}
constexpr int part_lmax(int part) {
    int mx = 0;
    for (int l = 0; l <= LMAX; ++l)
        if (PART_OF_L[l] == part) mx = l;
    return mx;
}
constexpr int slot_r(int part, int l, int m) { return slot_base(part, l) + m; }
constexpr int slot_i(int part, int l, int m) { return slot_base(part, l) + (l + 1) + (m - 1); }

constexpr int MAXNA = 34;

struct Tables {
    int   map[NPART][MAXNA];
    float scl[NPART][MAXNA];
};
constexpr Tables make_tables() {
    Tables t{};
    for (int part = 0; part < NPART; ++part) {
        for (int l = 0; l <= LMAX; ++l) {
            if (PART_OF_L[l] != part) continue;
            for (int m = 0; m <= l; ++m) {
                const int    k     = slot_r(part, l, m);
                const double scale = csqrt(dfact(l + m) * dfact(l - m)) * csqrt((2 * l + 1) / (4.0 * PI_D));
                if (m == 0) {
                    t.map[part][k] = l * l + l;
                    t.scl[part][k] = (float)scale;
                } else {
                    const double f = csqrt(2.0) * ((m & 1) ? -1.0 : 1.0);
                    t.map[part][k] = l * l + l + m;
                    t.scl[part][k] = (float)(f * scale);
                }
            }
            for (int m = 1; m <= l; ++m) {
                const int    k     = slot_i(part, l, m);
                const double scale = csqrt(dfact(l + m) * dfact(l - m)) * csqrt((2 * l + 1) / (4.0 * PI_D));
                const double f     = csqrt(2.0) * ((m & 1) ? -1.0 : 1.0);
                t.map[part][k] = l * l + l - m;
                t.scl[part][k] = (float)(f * scale);
            }
        }
    }
    return t;
}
__constant__ Tables c_tab = make_tables();

}  // namespace

// Algebra (exact in fp): reference's z2 = (x/2,-y/2) = -conj(z1), z1 = (-x/2,-y/2).
//   zreal = z1r[p]^2 - z1i[q]^2                      -> u[p,q] = sr[p]-si[q]
//   zimag = (-1)^q * (zi[p]zr[q] - zr[p]zi[q])       -> v[p,q], sign into coef
// Every (l,m,p) term is then exactly 1 fma with an SGPR-resident coefficient.
template <int PART>
__device__ __forceinline__ void do_point(float x, float y, float z0, float* acc, const Coefs& C) {
    constexpr int PL = part_lmax(PART);

    const float r2  = x * x + y * y + z0 * z0;
    const float nrm = __builtin_amdgcn_sqrtf(r2);
    const float w0  = (r2 > 0.f) ? z0 : 0.f;  // x0 * mask

    float zr[PL + 1], zi[PL + 1];
    zr[0] = 1.f;
    zi[0] = 0.f;
    const float ar = -0.5f * x, ai = -0.5f * y;
#pragma unroll
    for (int p = 1; p <= PL; ++p) {
        zr[p] = ar * zr[p - 1] - ai * zi[p - 1];
        zi[p] = ar * zi[p - 1] + ai * zr[p - 1];
    }
    float sr[PL + 1], si[PL / 2 + 1];
#pragma unroll
    for (int p = 0; p <= PL; ++p) sr[p] = zr[p] * zr[p];
#pragma unroll
    for (int q = 0; q <= PL / 2; ++q) si[q] = zi[q] * zi[q];

    float u[pu_count()], v[pv_count()];
#pragma unroll
    for (int p = 0; p <= PL; ++p) {
#pragma unroll
        for (int q = 0; q <= LMAX; ++q) {
            if (q <= p && p + q <= PL) u[pu_idx(p, q)] = sr[p] - si[q];
            if (q < p && p + q <= PL) v[pv_idx(p, q)] = zi[p] * zr[q] - zr[p] * zi[q];
        }
    }

    float rp[PL + 1];
    rp[0] = 1.f;
#pragma unroll
    for (int l = 1; l <= PL; ++l) rp[l] = rp[l - 1] * nrm;

#pragma unroll
    for (int l = 0; l <= LMAX; ++l) {
        if (PART_OF_L[l] != PART) continue;  // compile-time eliminated
        const float wrl = w0 * rp[l];
#pragma unroll
        for (int m = 0; m <= l; ++m) {
            float shr = 0.f, shi = 0.f;
#pragma unroll
            for (int p = m; 2 * p <= l + m; ++p) {
                const int q = p - m;
                shr = fmaf(C.v[cidx_r(l, m, p)], u[pu_idx(p, q)], shr);
                if (m > 0) shi = fmaf(C.v[cidx_i(l, m, p)], v[pv_idx(p, q)], shi);
            }
            acc[slot_r(PART, l, m)] = fmaf(wrl, shr, acc[slot_r(PART, l, m)]);
            if (m > 0) acc[slot_i(PART, l, m)] = fmaf(wrl, shi, acc[slot_i(PART, l, m)]);
        }
    }
}

template <int PART>
__device__ __forceinline__ void sht_part(const float* __restrict__ pos, float* __restrict__ out,
                                         int n, int nblk, const Coefs& C) {
    constexpr int NA = nacc_part(PART);

    float acc[NA];
#pragma unroll
    for (int k = 0; k < NA; ++k) acc[k] = 0.f;

    const int bid    = (int)(blockIdx.x >> 2);
    const int tid    = bid * 256 + (int)threadIdx.x;
    const int stride = nblk * 256;
    const int nq     = (n + 3) >> 2;  // quads of 4 points

    const float4* p4 = (const float4*)pos;

    for (int qd = tid; qd < nq; qd += stride) {
        float4 A, B, D;
        if (4 * qd + 3 < n) {  // 3 x dwordx4 = 4 points
            A = p4[3 * qd + 0];
            B = p4[3 * qd + 1];
            D = p4[3 * qd + 2];
        } else {  // boundary quad: per-point guarded; OOB -> (0,0,0) contributes 0
            float t[12];
#pragma unroll
            for (int j = 0; j < 4; ++j) {
                const int  pi = 4 * qd + j;
                const bool ok = pi < n;
                t[3 * j + 0] = ok ? pos[3 * pi + 0] : 0.f;
                t[3 * j + 1] = ok ? pos[3 * pi + 1] : 0.f;
                t[3 * j + 2] = ok ? pos[3 * pi + 2] : 0.f;
            }
            A = make_float4(t[0], t[1], t[2], t[3]);
            B = make_float4(t[4], t[5], t[6], t[7]);
            D = make_float4(t[8], t[9], t[10], t[11]);
        }
        do_point<PART>(A.x, A.y, A.z, acc, C);
        do_point<PART>(A.w, B.x, B.y, acc, C);
        do_point<PART>(B.z, B.w, D.x, acc, C);
        do_point<PART>(D.y, D.z, D.w, acc, C);
    }

    // Wave (64-lane) shuffle reduction, then cross-wave via LDS.
    __shared__ float red[4][NA];
    const int lane = threadIdx.x & 63;
    const int wav  = threadIdx.x >> 6;
#pragma unroll
    for (int k = 0; k < NA; ++k) {
        float v = acc[k];
#pragma unroll
        for (int off = 32; off > 0; off >>= 1) v += __shfl_down(v, off, 64);
        if (lane == 0) red[wav][k] = v;
    }
    __syncthreads();
    if ((int)threadIdx.x < NA) {
        const int   k = (int)threadIdx.x;
        const float v = red[0][k] + red[1][k] + red[2][k] + red[3][k];
        atomicAdd(&out[c_tab.map[PART][k]], v * c_tab.scl[PART][k]);
    }
}

__global__ __launch_bounds__(256, 4) void sht_kernel(const float* __restrict__ pos,
                                                     float* __restrict__ out, int n, int nblk,
                                                     Coefs C) {
    // part = blockIdx & 3: with round-robin dispatch over 256 CUs (0 mod 4),
    // all resident blocks on one CU share a part -> I$ locality.
    switch (blockIdx.x & 3) {
        case 0: sht_part<0>(pos, out, n, nblk, C); break;
        case 1: sht_part<1>(pos, out, n, nblk, C); break;
        case 2: sht_part<2>(pos, out, n, nblk, C); break;
        default: sht_part<3>(pos, out, n, nblk, C); break;
    }
}

extern "C" void kernel_launch(void* const* d_in, const int* in_sizes, int n_in,
                              void* d_out, int out_size, void* d_ws, size_t ws_size,
                              hipStream_t stream) {
    const float* pos = (const float*)d_in[0];
    float* out       = (float*)d_out;
    const int n      = in_sizes[0] / 3;  // (N,3) flat -> N points

    // d_out is poisoned before every launch; we accumulate via atomics.
    hipMemsetAsync(d_out, 0, (size_t)out_size * sizeof(float), stream);

    const int threads       = 256;
    const int nblk_per_part = 512;
    const int blocks        = NPART * nblk_per_part;  // 2048
    sht_kernel<<<blocks, threads, 0, stream>>>(pos, out, n, nblk_per_part, COEF_ARG);
}

// Round 4
// 475.414 us; speedup vs baseline: 1.4683x; 1.4683x over previous
//
#include <hip/hip_runtime.h>

namespace {

constexpr int LMAX = 10;
// 2-part split: even l -> part 0 (no sqrt needed: r^l = (r2)^(l/2)), odd l -> part 1
constexpr int PART_OF_L[LMAX + 1] = {0, 1, 0, 1, 0, 1, 0, 1, 0, 1, 0};
constexpr double PI_D = 3.14159265358979323846;

constexpr double FACT[LMAX + 1] = {1., 1., 2., 6., 24., 120., 720., 5040., 40320., 362880., 3628800.};

constexpr double dfact(int n) {
    double r = 1.0;
    for (int i = 2; i <= n; ++i) r *= (double)i;
    return r;
}
constexpr double csqrt(double x) {
    if (x <= 0.0) return 0.0;
    double g = x > 1.0 ? x : 1.0;
    for (int i = 0; i < 100; ++i) g = 0.5 * (g + x / g);
    return g;
}

// Term coefficients as compile-time literals (round-2 proven path: LLVM emits
// v_fmac_f32 dst, <literal>, vsrc -- VOP2 literal src0 is legal; NO kernarg
// struct, NO scratch).
constexpr float coef_r(int l, int m, int p) {
    const int q = p - m, s = l - p - q;
    return (float)(1.0 / (FACT[p] * FACT[q] * FACT[s]));
}
constexpr float coef_i(int l, int m, int p) {
    const int   q = p - m;
    const float c = coef_r(l, m, p);
    return (q & 1) ? -c : c;  // (-1)^q folded (z2 = -conj(z1), exact in fp)
}

// v-pair enumeration: p>q, p+q<=PL (each pair reused by every l>=p+q in part)
template <int PL>
constexpr int pv_count_() {
    int c = 0;
    for (int p = 1; p <= PL; ++p)
        for (int q = 0; q < p; ++q)
            if (p + q <= PL) ++c;
    return c;
}
template <int PL>
constexpr int pv_idx_(int p, int q) {
    int c = 0;
    for (int pp = 1; pp <= PL; ++pp)
        for (int qq = 0; qq < pp; ++qq) {
            if (pp + qq > PL) continue;
            if (pp == p && qq == q) return c;
            ++c;
        }
    return -1;
}

// ---- per-part accumulator slot layout ------------------------------------
constexpr int slot_base(int part, int l) {
    int c = 0;
    for (int ll = 0; ll < l; ++ll)
        if (PART_OF_L[ll] == part) c += 2 * ll + 1;
    return c;
}
constexpr int nacc_part(int part) {
    int c = 0;
    for (int l = 0; l <= LMAX; ++l)
        if (PART_OF_L[l] == part) c += 2 * l + 1;
    return c;
}
constexpr int part_lmax(int part) {
    int mx = 0;
    for (int l = 0; l <= LMAX; ++l)
        if (PART_OF_L[l] == part) mx = l;
    return mx;
}
constexpr int slot_r(int part, int l, int m) { return slot_base(part, l) + m; }
constexpr int slot_i(int part, int l, int m) { return slot_base(part, l) + (l + 1) + (m - 1); }

constexpr int MAXNA = 66;  // part 0

struct Tables {
    int   map[2][MAXNA];
    float scl[2][MAXNA];
};
constexpr Tables make_tables() {
    Tables t{};
    for (int part = 0; part < 2; ++part) {
        for (int l = 0; l <= LMAX; ++l) {
            if (PART_OF_L[l] != part) continue;
            for (int m = 0; m <= l; ++m) {
                const int    k     = slot_r(part, l, m);
                const double scale = csqrt(dfact(l + m) * dfact(l - m)) * csqrt((2 * l + 1) / (4.0 * PI_D));
                if (m == 0) {
                    t.map[part][k] = l * l + l;
                    t.scl[part][k] = (float)scale;
                } else {
                    const double f = csqrt(2.0) * ((m & 1) ? -1.0 : 1.0);
                    t.map[part][k] = l * l + l + m;
                    t.scl[part][k] = (float)(f * scale);
                }
            }
            for (int m = 1; m <= l; ++m) {
                const int    k     = slot_i(part, l, m);
                const double scale = csqrt(dfact(l + m) * dfact(l - m)) * csqrt((2 * l + 1) / (4.0 * PI_D));
                const double f     = csqrt(2.0) * ((m & 1) ? -1.0 : 1.0);
                t.map[part][k] = l * l + l - m;
                t.scl[part][k] = (float)(f * scale);
            }
        }
    }
    return t;
}
__constant__ Tables c_tab = make_tables();

}  // namespace

// Algebra (exact in fp): reference's z2 = (x/2,-y/2) = -conj(z1), z1 = (-x/2,-y/2).
//   zreal = z1r[p]^2 - z1i[q]^2                 -> inline (SR[p]-SI[q]) sub+fma
//   zimag = (-1)^q (zi[p]zr[q] - zr[p]zi[q])    -> v[p,q] precomputed, 1 fma/term
template <int PART>
__device__ __forceinline__ void do_point(float x, float y, float z0, float* acc) {
    constexpr int PL = part_lmax(PART);  // 10 (even) or 9 (odd)

    const float r2 = x * x + y * y + z0 * z0;
    const float w0 = (r2 > 0.f) ? z0 : 0.f;  // x0 * mask

    // Powers of z1 = (-x/2, -y/2) (repeated complex multiply, matches ref)
    float zr[PL + 1], zi[PL + 1];
    zr[0] = 1.f;
    zi[0] = 0.f;
    const float ar = -0.5f * x, ai = -0.5f * y;
#pragma unroll
    for (int p = 1; p <= PL; ++p) {
        zr[p] = zr[p - 1] * ar - zi[p - 1] * ai;
        zi[p] = zi[p - 1] * ar + zr[p - 1] * ai;
    }

    // Imag pair values (reused by ~4 l's each); zr/zi die after this + squares.
    float v[pv_count_<PL>()];
#pragma unroll
    for (int p = 1; p <= PL; ++p) {
#pragma unroll
        for (int q = 0; q < p; ++q) {
            if (p + q <= PL) v[pv_idx_<PL>(p, q)] = zi[p] * zr[q] - zr[p] * zi[q];
        }
    }

    float SR[PL + 1], SI[PL / 2 + 1];
#pragma unroll
    for (int p = 0; p <= PL; ++p) SR[p] = zr[p] * zr[p];
#pragma unroll
    for (int q = 0; q <= PL / 2; ++q) SI[q] = zi[q] * zi[q];

    // r^l chain: consecutive l in a part differ by 2 -> multiply by r2.
    float rl;
    if (PART == 0) {
        rl = 1.f;  // even powers: no sqrt needed at all
    } else {
        rl = sqrtf(r2);  // r^1
    }

#pragma unroll
    for (int l = 0; l <= LMAX; ++l) {
        if (PART_OF_L[l] != PART) continue;  // compile-time eliminated
        const float wrl = w0 * rl;
        rl *= r2;
#pragma unroll
        for (int m = 0; m <= l; ++m) {
            float shr = 0.f, shi = 0.f;
#pragma unroll
            for (int p = m; 2 * p <= l + m; ++p) {
                const int q = p - m;
                shr = fmaf(SR[p] - SI[q], coef_r(l, m, p), shr);
                if (m > 0) shi = fmaf(v[pv_idx_<PL>(p, q)], coef_i(l, m, p), shi);
            }
            acc[slot_r(PART, l, m)] = fmaf(wrl, shr, acc[slot_r(PART, l, m)]);
            if (m > 0) acc[slot_i(PART, l, m)] = fmaf(wrl, shi, acc[slot_i(PART, l, m)]);
        }
    }
}

template <int PART>
__device__ __forceinline__ void sht_part(const float* __restrict__ pos, float* __restrict__ out,
                                         int n, int bid, int nblk) {
    constexpr int NA = nacc_part(PART);

    float acc[NA];
#pragma unroll
    for (int k = 0; k < NA; ++k) acc[k] = 0.f;

    const int tid    = bid * 256 + (int)threadIdx.x;
    const int stride = nblk * 256;
    const int npair  = (n + 1) >> 1;  // 2 points / iter

    const float2* p2 = (const float2*)pos;

    for (int pr = tid; pr < npair; pr += stride) {
        // pair = points 2pr, 2pr+1: floats [6pr..6pr+5] as 3 x float2
        float2 a, b, c;
        if (2 * pr + 1 < n) {
            a = p2[3 * pr + 0];
            b = p2[3 * pr + 1];
            c = p2[3 * pr + 2];
        } else {  // odd tail: single point, second contributes 0
            a.x = pos[6 * pr + 0];
            a.y = pos[6 * pr + 1];
            b.x = pos[6 * pr + 2];
            b.y = 0.f;
            c.x = 0.f;
            c.y = 0.f;
        }
        do_point<PART>(a.x, a.y, b.x, acc);
        do_point<PART>(b.y, c.x, c.y, acc);
    }

    // Wave (64-lane) shuffle reduction, then cross-wave via LDS.
    __shared__ float red[4][NA];
    const int lane = threadIdx.x & 63;
    const int wav  = threadIdx.x >> 6;
#pragma unroll
    for (int k = 0; k < NA; ++k) {
        float s = acc[k];
#pragma unroll
        for (int off = 32; off > 0; off >>= 1) s += __shfl_down(s, off, 64);
        if (lane == 0) red[wav][k] = s;
    }
    __syncthreads();
    if ((int)threadIdx.x < NA) {
        const int   k = (int)threadIdx.x;
        const float s = red[0][k] + red[1][k] + red[2][k] + red[3][k];
        atomicAdd(&out[c_tab.map[PART][k]], s * c_tab.scl[PART][k]);
    }
}

// waves_per_eu(4,4): max=4 tells the allocator 8 waves/SIMD is impossible, so
// it uses the full 128-VGPR budget instead of squeezing to 64 (rounds 2/3 both
// show the default heuristic picking 64 and starving temps).
__global__ __launch_bounds__(256) __attribute__((amdgpu_waves_per_eu(4, 4)))
void sht_kernel(const float* __restrict__ pos, float* __restrict__ out, int n, int nA, int nB) {
    const int b = (int)blockIdx.x;
    if (b < nA) {
        sht_part<0>(pos, out, n, b, nA);
    } else {
        sht_part<1>(pos, out, n, b - nA, nB);
    }
}

extern "C" void kernel_launch(void* const* d_in, const int* in_sizes, int n_in,
                              void* d_out, int out_size, void* d_ws, size_t ws_size,
                              hipStream_t stream) {
    const float* pos = (const float*)d_in[0];
    float* out       = (float*)d_out;
    const int n      = in_sizes[0] / 3;  // (N,3) flat -> N points

    // d_out is poisoned before every launch; we accumulate via atomics.
    hipMemsetAsync(d_out, 0, (size_t)out_size * sizeof(float), stream);

    // 1024 blocks = exactly 4 blocks/CU at 4 waves/SIMD (full residency, one
    // dispatch round). Split 576/448 ~ per-part cost ratio (~440:370 inst/pt).
    const int nA = 576, nB = 448;
    sht_kernel<<<nA + nB, 256, 0, stream>>>(pos, out, n, nA, nB);
}

// Round 5
// 186.971 us; speedup vs baseline: 3.7334x; 2.5427x over previous
//
#include <hip/hip_runtime.h>

namespace {

constexpr int LMAX  = 10;
constexpr int NPART = 4;
// Greedy-balanced partition of l into 4 parts by inner-term count:
// P0{10,3}, P1{9,4}, P2{8,5,1}, P3{7,6,2,0}
constexpr int PART_OF_L[LMAX + 1] = {3, 2, 3, 0, 1, 2, 3, 3, 2, 1, 0};
constexpr double PI_D = 3.14159265358979323846;

constexpr double FACT[LMAX + 1] = {1., 1., 2., 6., 24., 120., 720., 5040., 40320., 362880., 3628800.};

constexpr double dfact(int n) {
    double r = 1.0;
    for (int i = 2; i <= n; ++i) r *= (double)i;
    return r;
}
constexpr double csqrt(double x) {
    if (x <= 0.0) return 0.0;
    double g = x > 1.0 ? x : 1.0;
    for (int i = 0; i < 100; ++i) g = 0.5 * (g + x / g);
    return g;
}

// ---- term coefficients ----------------------------------------------------
constexpr float coef_r(int l, int m, int p) {
    const int q = p - m, s = l - p - q;
    return (float)(1.0 / (FACT[p] * FACT[q] * FACT[s]));
}
constexpr float coef_i(int l, int m, int p) {
    const int   q = p - m;
    const float c = coef_r(l, m, p);
    return (q & 1) ? -c : c;  // (-1)^q folded (z2 = -conj(z1), exact in fp)
}

// Dedup all signed coefficient values. Stored in __constant__ memory (NOT a
// kernarg struct -- round 3 showed by-value structs land in per-thread
// scratch). Constexpr-indexed access -> s_load -> SGPR operand in v_fmac:
// zero VALU issue slots for coefficient materialization.
constexpr int MAXC = 340;
struct CoefsN {
    float v[MAXC];
    int   n;
};
constexpr CoefsN build_coefs() {
    CoefsN b{};
    b.n = 0;
    for (int l = 0; l <= LMAX; ++l)
        for (int m = 0; m <= l; ++m)
            for (int p = m; 2 * p <= l + m; ++p) {
                const float cr = coef_r(l, m, p);
                bool found = false;
                for (int i = 0; i < b.n; ++i)
                    if (b.v[i] == cr) { found = true; break; }
                if (!found) b.v[b.n++] = cr;
                if (m > 0) {
                    const float ci = coef_i(l, m, p);
                    found = false;
                    for (int i = 0; i < b.n; ++i)
                        if (b.v[i] == ci) { found = true; break; }
                    if (!found) b.v[b.n++] = ci;
                }
            }
    return b;
}
constexpr CoefsN CB = build_coefs();
constexpr int    NC = CB.n;

struct Coefs {
    float v[NC];
};
constexpr Coefs make_coef_arr() {
    Coefs c{};
    for (int i = 0; i < NC; ++i) c.v[i] = CB.v[i];
    return c;
}
__constant__ Coefs c_coef = make_coef_arr();

constexpr int cfind(float x) {
    for (int i = 0; i < CB.n; ++i)
        if (CB.v[i] == x) return i;
    return -1;
}
constexpr int cidx_r(int l, int m, int p) { return cfind(coef_r(l, m, p)); }
constexpr int cidx_i(int l, int m, int p) { return cfind(coef_i(l, m, p)); }

// ---- pair enumerations (u: p>=q, v: p>q; p+q<=LMAX) -----------------------
constexpr int pu_idx(int p, int q) {
    int idx = 0;
    for (int pp = 0; pp <= LMAX; ++pp)
        for (int qq = 0; qq <= pp; ++qq) {
            if (pp + qq > LMAX) continue;
            if (pp == p && qq == q) return idx;
            ++idx;
        }
    return -1;
}
constexpr int pu_count() {
    int idx = 0;
    for (int pp = 0; pp <= LMAX; ++pp)
        for (int qq = 0; qq <= pp; ++qq)
            if (pp + qq <= LMAX) ++idx;
    return idx;
}
constexpr int pv_idx(int p, int q) {
    int idx = 0;
    for (int pp = 0; pp <= LMAX; ++pp)
        for (int qq = 0; qq < pp; ++qq) {
            if (pp + qq > LMAX) continue;
            if (pp == p && qq == q) return idx;
            ++idx;
        }
    return -1;
}
constexpr int pv_count() {
    int idx = 0;
    for (int pp = 0; pp <= LMAX; ++pp)
        for (int qq = 0; qq < pp; ++qq)
            if (pp + qq <= LMAX) ++idx;
    return idx;
}

// ---- per-part accumulator slot layout ------------------------------------
constexpr int slot_base(int part, int l) {
    int c = 0;
    for (int ll = 0; ll < l; ++ll)
        if (PART_OF_L[ll] == part) c += 2 * ll + 1;
    return c;
}
constexpr int nacc_part(int part) {
    int c = 0;
    for (int l = 0; l <= LMAX; ++l)
        if (PART_OF_L[l] == part) c += 2 * l + 1;
    return c;
}
constexpr int part_lmax(int part) {
    int mx = 0;
    for (int l = 0; l <= LMAX; ++l)
        if (PART_OF_L[l] == part) mx = l;
    return mx;
}
constexpr int slot_r(int part, int l, int m) { return slot_base(part, l) + m; }
constexpr int slot_i(int part, int l, int m) { return slot_base(part, l) + (l + 1) + (m - 1); }

constexpr int MAXNA = 34;

struct Tables {
    int   map[NPART][MAXNA];
    float scl[NPART][MAXNA];
};
constexpr Tables make_tables() {
    Tables t{};
    for (int part = 0; part < NPART; ++part) {
        for (int l = 0; l <= LMAX; ++l) {
            if (PART_OF_L[l] != part) continue;
            for (int m = 0; m <= l; ++m) {
                const int    k     = slot_r(part, l, m);
                const double scale = csqrt(dfact(l + m) * dfact(l - m)) * csqrt((2 * l + 1) / (4.0 * PI_D));
                if (m == 0) {
                    t.map[part][k] = l * l + l;
                    t.scl[part][k] = (float)scale;
                } else {
                    const double f = csqrt(2.0) * ((m & 1) ? -1.0 : 1.0);
                    t.map[part][k] = l * l + l + m;
                    t.scl[part][k] = (float)(f * scale);
                }
            }
            for (int m = 1; m <= l; ++m) {
                const int    k     = slot_i(part, l, m);
                const double scale = csqrt(dfact(l + m) * dfact(l - m)) * csqrt((2 * l + 1) / (4.0 * PI_D));
                const double f     = csqrt(2.0) * ((m & 1) ? -1.0 : 1.0);
                t.map[part][k] = l * l + l - m;
                t.scl[part][k] = (float)(f * scale);
            }
        }
    }
    return t;
}
__constant__ Tables c_tab = make_tables();

}  // namespace

// Algebra (exact in fp): reference's z2 = (x/2,-y/2) = -conj(z1), z1 = (-x/2,-y/2).
//   zreal = z1r[p]^2 - z1i[q]^2                      -> u[p,q] = sr[p]-si[q]
//   zimag = (-1)^q * (zi[p]zr[q] - zr[p]zi[q])       -> v[p,q], sign into coef
// Every (l,m,p) term: exactly 1 v_fmac with an SGPR-resident coefficient.
template <int PART>
__device__ __forceinline__ void do_point(float x, float y, float z0, float* acc) {
    constexpr int PL = part_lmax(PART);

    const float r2  = x * x + y * y + z0 * z0;
    const float nrm = sqrtf(r2);
    const float w0  = (r2 > 0.f) ? z0 : 0.f;  // x0 * mask

    float zr[PL + 1], zi[PL + 1];
    zr[0] = 1.f;
    zi[0] = 0.f;
    const float ar = -0.5f * x, ai = -0.5f * y;
#pragma unroll
    for (int p = 1; p <= PL; ++p) {
        zr[p] = zr[p - 1] * ar - zi[p - 1] * ai;
        zi[p] = zi[p - 1] * ar + zr[p - 1] * ai;
    }
    float sr[PL + 1], si[PL / 2 + 1];
#pragma unroll
    for (int p = 0; p <= PL; ++p) sr[p] = zr[p] * zr[p];
#pragma unroll
    for (int q = 0; q <= PL / 2; ++q) si[q] = zi[q] * zi[q];

    float u[pu_count()], v[pv_count()];
#pragma unroll
    for (int p = 0; p <= PL; ++p) {
#pragma unroll
        for (int q = 0; q <= LMAX; ++q) {
            if (q <= p && p + q <= PL) u[pu_idx(p, q)] = sr[p] - si[q];
            if (q < p && p + q <= PL) v[pv_idx(p, q)] = zi[p] * zr[q] - zr[p] * zi[q];
        }
    }

    float rp[PL + 1];
    rp[0] = 1.f;
#pragma unroll
    for (int l = 1; l <= PL; ++l) rp[l] = rp[l - 1] * nrm;

#pragma unroll
    for (int l = 0; l <= LMAX; ++l) {
        if (PART_OF_L[l] != PART) continue;  // compile-time eliminated
        const float wrl = w0 * rp[l];
#pragma unroll
        for (int m = 0; m <= l; ++m) {
            float shr = 0.f, shi = 0.f;
#pragma unroll
            for (int p = m; 2 * p <= l + m; ++p) {
                const int q = p - m;
                shr = fmaf(c_coef.v[cidx_r(l, m, p)], u[pu_idx(p, q)], shr);
                if (m > 0) shi = fmaf(c_coef.v[cidx_i(l, m, p)], v[pv_idx(p, q)], shi);
            }
            acc[slot_r(PART, l, m)] = fmaf(wrl, shr, acc[slot_r(PART, l, m)]);
            if (m > 0) acc[slot_i(PART, l, m)] = fmaf(wrl, shi, acc[slot_i(PART, l, m)]);
        }
    }
}

template <int PART>
__device__ __forceinline__ void sht_part(const float* __restrict__ pos, float* __restrict__ out,
                                         int n, int nblk) {
    constexpr int NA = nacc_part(PART);

    float acc[NA];
#pragma unroll
    for (int k = 0; k < NA; ++k) acc[k] = 0.f;

    const int bid    = (int)(blockIdx.x >> 2);
    const int tid    = bid * 256 + (int)threadIdx.x;
    const int stride = nblk * 256;
    const int nq     = (n + 3) >> 2;  // quads of 4 points

    const float4* p4 = (const float4*)pos;

    for (int qd = tid; qd < nq; qd += stride) {
        float4 A, B, D;
        if (4 * qd + 3 < n) {  // 3 x dwordx4 = 4 points
            A = p4[3 * qd + 0];
            B = p4[3 * qd + 1];
            D = p4[3 * qd + 2];
        } else {  // boundary quad: per-point guarded; OOB -> (0,0,0) contributes 0
            float t[12];
#pragma unroll
            for (int j = 0; j < 4; ++j) {
                const int  pi = 4 * qd + j;
                const bool ok = pi < n;
                t[3 * j + 0] = ok ? pos[3 * pi + 0] : 0.f;
                t[3 * j + 1] = ok ? pos[3 * pi + 1] : 0.f;
                t[3 * j + 2] = ok ? pos[3 * pi + 2] : 0.f;
            }
            A = make_float4(t[0], t[1], t[2], t[3]);
            B = make_float4(t[4], t[5], t[6], t[7]);
            D = make_float4(t[8], t[9], t[10], t[11]);
        }
        do_point<PART>(A.x, A.y, A.z, acc);
        do_point<PART>(A.w, B.x, B.y, acc);
        do_point<PART>(B.z, B.w, D.x, acc);
        do_point<PART>(D.y, D.z, D.w, acc);
    }

    // Wave (64-lane) shuffle reduction, then cross-wave via LDS.
    __shared__ float red[4][NA];
    const int lane = threadIdx.x & 63;
    const int wav  = threadIdx.x >> 6;
#pragma unroll
    for (int k = 0; k < NA; ++k) {
        float s = acc[k];
#pragma unroll
        for (int off = 32; off > 0; off >>= 1) s += __shfl_down(s, off, 64);
        if (lane == 0) red[wav][k] = s;
    }
    __syncthreads();
    if ((int)threadIdx.x < NA) {
        const int   k = (int)threadIdx.x;
        const float s = red[0][k] + red[1][k] + red[2][k] + red[3][k];
        atomicAdd(&out[c_tab.map[PART][k]], s * c_tab.scl[PART][k]);
    }
}

__global__ __launch_bounds__(256) void sht_kernel(const float* __restrict__ pos,
                                                  float* __restrict__ out, int n, int nblk) {
    // part = blockIdx & 3: with round-robin dispatch over 256 CUs (0 mod 4),
    // all resident blocks on one CU share a part -> I$ locality.
    switch (blockIdx.x & 3) {
        case 0: sht_part<0>(pos, out, n, nblk); break;
        case 1: sht_part<1>(pos, out, n, nblk); break;
        case 2: sht_part<2>(pos, out, n, nblk); break;
        default: sht_part<3>(pos, out, n, nblk); break;
    }
}

extern "C" void kernel_launch(void* const* d_in, const int* in_sizes, int n_in,
                              void* d_out, int out_size, void* d_ws, size_t ws_size,
                              hipStream_t stream) {
    const float* pos = (const float*)d_in[0];
    float* out       = (float*)d_out;
    const int n      = in_sizes[0] / 3;  // (N,3) flat -> N points

    // d_out is poisoned before every launch; we accumulate via atomics.
    hipMemsetAsync(d_out, 0, (size_t)out_size * sizeof(float), stream);

    const int threads       = 256;
    const int nblk_per_part = 512;
    const int blocks        = NPART * nblk_per_part;  // 2048
    sht_kernel<<<blocks, threads, 0, stream>>>(pos, out, n, nblk_per_part);
}